// Round 22
// baseline (1238.418 us; speedup 1.0000x reference)
//
#include <hip/hip_runtime.h>

#define EPSF 1e-5f

typedef _Float16 h2f  __attribute__((ext_vector_type(2)));
typedef _Float16 h8   __attribute__((ext_vector_type(8)));
typedef float    f32x4 __attribute__((ext_vector_type(4)));

#if defined(__has_builtin)
#if __has_builtin(__builtin_amdgcn_fdot2)
#define HAVE_FDOT2 1
#endif
#endif

__device__ __forceinline__ float fsig(float x){ return 1.0f/(1.0f+__expf(-x)); }
__device__ __forceinline__ float ftanh(float x){
  float e = __expf(2.f*x);
  float r = (e-1.f)/(e+1.f);
  return (x > 15.f) ? 1.f : ((x < -15.f) ? -1.f : r);
}
__device__ __forceinline__ int pkf(float lo, float hi){
  return __builtin_bit_cast(int, __builtin_amdgcn_cvt_pkrtz(lo, hi));
}
__device__ __forceinline__ int4 mk4(const float* p){
  return make_int4(pkf(p[0],p[1]),pkf(p[2],p[3]),pkf(p[4],p[5]),pkf(p[6],p[7]));
}
__device__ __forceinline__ float dot2(int w, int x, float acc){
#ifdef HAVE_FDOT2
  return __builtin_amdgcn_fdot2(__builtin_bit_cast(h2f, w),
                                __builtin_bit_cast(h2f, x), acc, false);
#else
  h2f a = __builtin_bit_cast(h2f, w), b = __builtin_bit_cast(h2f, x);
  return acc + (float)a[0]*(float)b[0] + (float)a[1]*(float)b[1];
#endif
}
__device__ __forceinline__ int rl_i(int v, int l){ return __builtin_amdgcn_readlane(v, l); }
__device__ __forceinline__ float rl_f(float v, int l){
  return __int_as_float(__builtin_amdgcn_readlane(__float_as_int(v), l));
}
#define MFMA(A,B,C) __builtin_amdgcn_mfma_f32_16x16x32_f16( \
    __builtin_bit_cast(h8,(A)), __builtin_bit_cast(h8,(B)), (C), 0,0,0)
// light barrier: order LDS only; global loads/stores stay in flight
#define BAR() do{ asm volatile("s_waitcnt lgkmcnt(0)" ::: "memory"); __builtin_amdgcn_s_barrier(); }while(0)

// ---------------------------------------------------------------------------
// Kernel 1: msum[t] = sum_{b,n} masks[b,t,n] + EPS   (one block per t)
// ---------------------------------------------------------------------------
__global__ void msum_kernel(const float* __restrict__ masks, float* __restrict__ msum){
  const int t   = blockIdx.x;
  const int tid = threadIdx.x;
  const int b0  = tid >> 3;
  const int n4  = (tid & 7) << 2;
  float s = 0.f;
  #pragma unroll 4
  for (int i = 0; i < 32; ++i) {
    const int b = b0 + (i << 5);
    const float4 v = *reinterpret_cast<const float4*>(masks + ((size_t)b*256 + t)*32 + n4);
    s += v.x + v.y + v.z + v.w;
  }
  __shared__ float red[256];
  red[tid] = s; __syncthreads();
  for (int off = 128; off > 0; off >>= 1) {
    if (tid < off) red[tid] += red[tid + off];
    __syncthreads();
  }
  if (tid == 0) msum[t] = red[0] + EPSF;
}

// ---------------------------------------------------------------------------
// Kernel 2: persistent RNN. 128 blocks x 1024 threads, 8 batch elems / block.
// r18 chain/E structure, widened: waves 0-7 = eight chains (SIMD s hosts
// chains s and s+4 -> TWO independent chain streams per SIMD, so LDS/
// bpermute/exp stalls of one interleave with issue of the other -- the
// first structure with >1 runnable wave/SIMD during the serial phase).
// Waves 8-15 = E: gate GEMM A rows 0..7 (8 elems, MFMA tile half-full);
// kg==0/1 lane groups hold C/D rows 0-3 / 4-7. gamma_h on E-waves 0-3,
// alpha on E-waves 4-5 (per-elem MFMA from prefetched inputs as in r18).
// ---------------------------------------------------------------------------
__global__ __launch_bounds__(1024, 1)
void rits_kernel(
  const float* __restrict__ values, const float* __restrict__ masks,
  const float* __restrict__ deltas, const float* __restrict__ labels,
  const float* __restrict__ is_train,
  const float* __restrict__ td_h_W, const float* __restrict__ td_h_b,
  const float* __restrict__ td_x_W, const float* __restrict__ td_x_b,
  const float* __restrict__ hist_W, const float* __restrict__ hist_b,
  const float* __restrict__ feat_W, const float* __restrict__ feat_b,
  const float* __restrict__ wc_W,  const float* __restrict__ wc_b,
  const float* __restrict__ W_ih,  const float* __restrict__ W_hh,
  const float* __restrict__ b_ih,  const float* __restrict__ b_hh,
  const float* __restrict__ out_W, const float* __restrict__ out_b,
  const float* __restrict__ msum,
  float* __restrict__ xl_acc, float* __restrict__ bce_acc,
  float* __restrict__ predictions, float* __restrict__ imps)
{
  // [e][ cc 0..15 | m 16..31 | h 32..63 ] packed f16 pairs; stride 84
  // (84%32=20 -> 8 row offsets mod 32 all distinct: conflict-free).
  __shared__ __align__(16) int  inp_s[8][84];
  // future words for E: [e][ dw 0..15 | gxw 16..31 | mw 32..47 ]; stride 52
  __shared__ __align__(16) int  nb[8][52];
  __shared__ float sB[8][64];     // gamma_h linear (pre-exp) for the step entered
  __shared__ float sAl[8][32];    // alpha for the step entered
  __shared__ float gp[8][256];    // [elem][gate row]  (raw, F activates)
  __shared__ float msum_l[256];   // 1/msum[t]

  const int tid = threadIdx.x;
  const int b   = blockIdx.x;
  const int wv  = tid >> 6;          // 0..15
  const int ln  = tid & 63;
  const bool chain = (wv < 8);
  const int me  = wv & 7;            // chain elem
  const int ew  = wv - 8;            // E-wave id (valid when !chain)
  const int b2  = (b << 3) | me;
  const int kg  = ln >> 4;
  const int arow = ln & 15;

  if (tid < 256) msum_l[tid] = 1.0f / msum[tid];

  // ---- E-wave fragments ----
  int4 Wb[2][4];
  float bs0 = 0.f, bs1 = 0.f; int col0 = 0;
  int4 fGh = make_int4(0,0,0,0);
  float ghb = 0.f; int colj = 0;
  int4 fA0 = make_int4(0,0,0,0), fA1 = make_int4(0,0,0,0);
  float alb = 0.f; int colA = 0;
  if (!chain){
    #pragma unroll
    for (int nt = 0; nt < 2; ++nt){
      const int col = (ew << 5) + (nt << 4) + (ln & 15);
      #pragma unroll
      for (int ks = 0; ks < 4; ++ks){
        const int k0 = (ks << 5) + (kg << 3);
        const float* src = (k0 < 64) ? (W_ih + (size_t)col*64 + k0)
                                     : (W_hh + (size_t)col*64 + (k0 - 64));
        Wb[nt][ks] = make_int4(pkf(src[0],src[1]), pkf(src[2],src[3]),
                               pkf(src[4],src[5]), pkf(src[6],src[7]));
      }
    }
    col0 = (ew << 5) + (ln & 15);
    bs0 = b_ih[col0]      + b_hh[col0];
    bs1 = b_ih[col0 + 16] + b_hh[col0 + 16];
    if (ew < 4){
      colj = (ew << 4) | (ln & 15);
      fGh  = mk4(td_h_W + colj*32 + kg*8);
      ghb  = td_h_b[colj];
    }
    if (ew == 4 || ew == 5){
      colA = ((ew - 4) << 4) | (ln & 15);
      fA0  = mk4(wc_W + colA*64 + kg*8);
      fA1  = mk4(wc_W + colA*64 + 32 + kg*8);
      alb  = wc_b[colA];
    }
  }

  // ---- chain-wave VGPR weights + registers ----
  int4  fC[8];      // hist_W row (ln&31) (K=64)
  float wz[32];     // feat_W row (ln&31), fp32, diag 0
  float tdxd_r=0.f, tdxb_r=0.f, histb_r=0.f, featb_r=0.f;
  float xv=0.f, mv=0.f, dv=0.f;
  if (chain){
    const int nr = ln & 31;
    #pragma unroll
    for (int g = 0; g < 8; ++g) fC[g] = mk4(hist_W + nr*64 + 8*g);
    #pragma unroll
    for (int k = 0; k < 32; ++k) wz[k] = (k==nr) ? 0.f : feat_W[nr*32 + k];
    if (ln < 32){
      tdxd_r  = td_x_W[ln*33];
      tdxb_r  = td_x_b[ln];
      histb_r = hist_b[ln];
      featb_r = feat_b[ln];
      const size_t base = (size_t)b2*8192 + ln;
      xv = values[base]; mv = masks[base]; dv = deltas[base];
    }
  }
  float h_reg = 0.f, c_reg = 0.f, loss_acc = 0.f;
  const int i0 = (2*ln) & 63, i1 = (2*ln+1) & 63;

  __syncthreads();

  // ---- prologue: nb(0) via b16 stores ; E computes sB(0), sAl(0) ----
  if (chain && ln < 32){
    _Float16* np = reinterpret_cast<_Float16*>(&nb[me][0]);
    const float gx0 = __expf(-fmaxf(fmaf(dv, tdxd_r, tdxb_r), 0.f));
    np[ln]      = (_Float16)dv;
    np[32 + ln] = (_Float16)gx0;
    np[64 + ln] = (_Float16)mv;
  }
  __syncthreads();
  if (!chain){
    if (ew < 4){
      int4 A = make_int4(0,0,0,0);
      if (arow < 8) A = *reinterpret_cast<const int4*>(&nb[arow][kg << 2]);
      f32x4 acc = {ghb, ghb, ghb, ghb};
      acc = MFMA(A, fGh, acc);
      if (kg < 2){
        #pragma unroll
        for (int e = 0; e < 4; ++e) sB[(kg<<2)+e][colj] = acc[e];
      }
    }
    if (ew == 4 || ew == 5){
      int4 A0 = make_int4(0,0,0,0), A1 = make_int4(0,0,0,0);
      if (arow < 8){
        A0 = *reinterpret_cast<const int4*>(&nb[arow][16 + (kg << 2)]);
        A1 = *reinterpret_cast<const int4*>(&nb[arow][32 + (kg << 2)]);
      }
      f32x4 aacc = {alb, alb, alb, alb};
      aacc = MFMA(A0, fA0, aacc);
      aacc = MFMA(A1, fA1, aacc);
      if (kg < 2){
        #pragma unroll
        for (int e = 0; e < 4; ++e) sAl[(kg<<2)+e][colA] = aacc[e];
      }
    }
  }
  __syncthreads();

  for (int t = 0; t < 256; ++t){
    // ---- chain: decay + C + z + combine; staging via b16 stores ----
    if (chain){
      const float x_cur = xv, m_cur = mv;
      const float sb = sB[me][ln];
      const float al = (ln < 32) ? sAl[me][ln] : 0.f;
      if (ln < 32 && t < 255){
        const size_t base = (size_t)b2*8192 + (size_t)(t+1)*32 + ln;
        xv = values[base]; mv = masks[base]; dv = deltas[base];
      }
      _Float16* hp = reinterpret_cast<_Float16*>(&inp_s[me][0]);
      _Float16* np = reinterpret_cast<_Float16*>(&nb[me][0]);

      h_reg *= __expf(-fmaxf(sb, 0.f));
      hp[64 + ln] = (_Float16)h_reg;        // h halves (words 32..63), direct
      const int hw = pkf(__shfl(h_reg, i0), __shfl(h_reg, i1));   // for C matvec
      // C: x_h (32 rows, K=64, VGPR weights); x_c
      float xh_v = 0.f, x_c_v = 0.f;
      if (ln < 32){
        float a0 = histb_r, a1 = 0.f, a2 = 0.f, a3 = 0.f;
        #pragma unroll
        for (int g4 = 0; g4 < 8; ++g4){
          const int4 w = fC[g4];
          a0 = dot2(w.x, rl_i(hw, 4*g4+0), a0);
          a1 = dot2(w.y, rl_i(hw, 4*g4+1), a1);
          a2 = dot2(w.z, rl_i(hw, 4*g4+2), a2);
          a3 = dot2(w.w, rl_i(hw, 4*g4+3), a3);
        }
        xh_v  = (a0+a1)+(a2+a3);
        x_c_v = m_cur*x_cur + (1.f-m_cur)*xh_v;
      }
      // D: z (fp32 readlane of x_c), combine with precomputed alpha
      if (ln < 32){
        float z0 = featb_r, z1 = 0.f, z2 = 0.f, z3 = 0.f;
        #pragma unroll
        for (int k = 0; k < 32; k += 4){
          z0 = fmaf(rl_f(x_c_v, k+0), wz[k+0], z0);
          z1 = fmaf(rl_f(x_c_v, k+1), wz[k+1], z1);
          z2 = fmaf(rl_f(x_c_v, k+2), wz[k+2], z2);
          z3 = fmaf(rl_f(x_c_v, k+3), wz[k+3], z3);
        }
        const float z = (z0+z1)+(z2+z3);
        const float ch = al*z + (1.f-al)*xh_v;
        loss_acc += (fabsf(x_cur-xh_v)+fabsf(x_cur-z)+fabsf(x_cur-ch))*m_cur*msum_l[t];
        const float ccv = m_cur*x_cur + (1.f-m_cur)*ch;
        imps[(size_t)b2*8192 + (size_t)t*32 + ln] = ccv;
        hp[ln]      = (_Float16)ccv;        // cc halves (words 0..15), direct
        hp[32 + ln] = (_Float16)m_cur;      // m halves (words 16..31), direct
        // future words for E (dv/mv hold t+1), direct b16
        const float gxn = __expf(-fmaxf(fmaf(dv, tdxd_r, tdxb_r), 0.f));
        np[ln]      = (_Float16)dv;
        np[32 + ln] = (_Float16)gxn;
        np[64 + ln] = (_Float16)mv;
      }
    }

    BAR();   // inp_s, nb visible to all waves

    // ---- E (waves 8-15): gate GEMM via MFMA, A rows 0..7 = 8 elems ----
    if (!chain){
      int4 A[4];
      if (arow < 8){
        #pragma unroll
        for (int ks = 0; ks < 4; ++ks)
          A[ks] = *reinterpret_cast<const int4*>(&inp_s[arow][(ks << 4) + (kg << 2)]);
      } else {
        #pragma unroll
        for (int ks = 0; ks < 4; ++ks) A[ks] = make_int4(0,0,0,0);
      }
      f32x4 acc0 = {bs0, bs0, bs0, bs0};
      f32x4 acc1 = {bs1, bs1, bs1, bs1};
      #pragma unroll
      for (int ks = 0; ks < 4; ++ks){
        acc0 = __builtin_amdgcn_mfma_f32_16x16x32_f16(
                 __builtin_bit_cast(h8, A[ks]), __builtin_bit_cast(h8, Wb[0][ks]), acc0, 0,0,0);
        acc1 = __builtin_amdgcn_mfma_f32_16x16x32_f16(
                 __builtin_bit_cast(h8, A[ks]), __builtin_bit_cast(h8, Wb[1][ks]), acc1, 0,0,0);
      }
      // C/D: col=lane&15, row=(lane>>4)*4+reg -> kg 0/1 hold rows 0-3/4-7
      if (kg < 2){
        #pragma unroll
        for (int e = 0; e < 4; ++e){
          gp[(kg<<2)+e][col0]      = acc0[e];
          gp[(kg<<2)+e][col0 + 16] = acc1[e];
        }
      }
      // gamma_h(t+1) (E-waves 0-3); alpha(t+1) (E-waves 4-5)
      if (ew < 4){
        int4 Agh = make_int4(0,0,0,0);
        if (arow < 8) Agh = *reinterpret_cast<const int4*>(&nb[arow][kg << 2]);
        f32x4 accg = {ghb, ghb, ghb, ghb};
        accg = MFMA(Agh, fGh, accg);
        if (kg < 2){
          #pragma unroll
          for (int e = 0; e < 4; ++e) sB[(kg<<2)+e][colj] = accg[e];
        }
      }
      if (ew == 4 || ew == 5){
        int4 A0 = make_int4(0,0,0,0), A1 = make_int4(0,0,0,0);
        if (arow < 8){
          A0 = *reinterpret_cast<const int4*>(&nb[arow][16 + (kg << 2)]);
          A1 = *reinterpret_cast<const int4*>(&nb[arow][32 + (kg << 2)]);
        }
        f32x4 aacc = {alb, alb, alb, alb};
        aacc = MFMA(A0, fA0, aacc);
        aacc = MFMA(A1, fA1, aacc);
        if (kg < 2){
          #pragma unroll
          for (int e = 0; e < 4; ++e) sAl[(kg<<2)+e][colA] = aacc[e];
        }
      }
    }

    BAR();   // gates + sB + sAl visible to chain waves

    // ---- F: LSTM pointwise update (chain waves) ----
    if (chain){
      const float ig = gp[me][ln];
      const float fg = gp[me][64+ln];
      const float gg = gp[me][128+ln];
      const float og = gp[me][192+ln];
      c_reg = fsig(fg)*c_reg + fsig(ig)*ftanh(gg);
      h_reg = fsig(og)*ftanh(c_reg);
    }
  }

  // ---- epilogue: loss reduce + prediction/BCE (chain waves) ----
  if (chain){
    float l = loss_acc;   // nonzero only on ln<32
    l += __shfl_xor(l,16); l += __shfl_xor(l,8);
    l += __shfl_xor(l,4);  l += __shfl_xor(l,2); l += __shfl_xor(l,1);
    if (ln == 0) atomicAdd(xl_acc, l);

    float p = h_reg * out_W[ln];
    p += __shfl_xor(p,32); p += __shfl_xor(p,16); p += __shfl_xor(p,8);
    p += __shfl_xor(p,4);  p += __shfl_xor(p,2);  p += __shfl_xor(p,1);
    if (ln == 0){
      const float y = p + out_b[0];
      predictions[b2] = fsig(y);
      const float lab = labels[b2];
      const float it  = is_train[b2];
      const float mx  = fmaxf(-y, 0.f);
      const float bce = y - y*lab + mx + __logf(__expf(-mx) + __expf(-y - mx));
      atomicAdd(bce_acc, bce * it);
    }
  }
}

// ---------------------------------------------------------------------------
// Kernel 3: finalize loss scalar
// ---------------------------------------------------------------------------
__global__ void final_kernel(const float* __restrict__ is_train,
                             const float* __restrict__ ws,
                             float* __restrict__ out){
  const int tid = threadIdx.x;
  __shared__ float red[256];
  red[tid] = is_train[tid] + is_train[tid+256] + is_train[tid+512] + is_train[tid+768];
  __syncthreads();
  for (int off = 128; off > 0; off >>= 1){
    if (tid < off) red[tid] += red[tid + off];
    __syncthreads();
  }
  if (tid == 0){
    const float yl = ws[1] / (red[0] + EPSF);
    out[0] = ws[0] / 256.0f + 0.1f * yl;
  }
}

extern "C" void kernel_launch(void* const* d_in, const int* in_sizes, int n_in,
                              void* d_out, int out_size, void* d_ws, size_t ws_size,
                              hipStream_t stream){
  const float* values   = (const float*)d_in[0];
  const float* masks    = (const float*)d_in[1];
  const float* deltas   = (const float*)d_in[2];
  const float* labels   = (const float*)d_in[5];
  const float* is_train = (const float*)d_in[6];
  const float* td_h_W   = (const float*)d_in[7];
  const float* td_h_b   = (const float*)d_in[8];
  const float* td_x_W   = (const float*)d_in[9];
  const float* td_x_b   = (const float*)d_in[10];
  const float* hist_W   = (const float*)d_in[11];
  const float* hist_b   = (const float*)d_in[12];
  const float* feat_W   = (const float*)d_in[13];
  const float* feat_b   = (const float*)d_in[14];
  const float* wc_W     = (const float*)d_in[15];
  const float* wc_b     = (const float*)d_in[16];
  const float* W_ih     = (const float*)d_in[17];
  const float* W_hh     = (const float*)d_in[18];
  const float* b_ih     = (const float*)d_in[19];
  const float* b_hh     = (const float*)d_in[20];
  const float* out_W    = (const float*)d_in[21];
  const float* out_b    = (const float*)d_in[22];

  float* out = (float*)d_out;                 // [0]=loss, [1..1025)=preds, [1025..)=imps
  float* ws  = (float*)d_ws;                  // [0]=xl_sum, [1]=bce_sum, [2..258)=msum

  hipMemsetAsync(ws, 0, 2*sizeof(float), stream);
  msum_kernel<<<256, 256, 0, stream>>>(masks, ws + 2);
  rits_kernel<<<128, 1024, 0, stream>>>(values, masks, deltas, labels, is_train,
      td_h_W, td_h_b, td_x_W, td_x_b, hist_W, hist_b, feat_W, feat_b,
      wc_W, wc_b, W_ih, W_hh, b_ih, b_hh, out_W, out_b,
      ws + 2, ws + 0, ws + 1, out + 1, out + 1 + 1024);
  final_kernel<<<1, 256, 0, stream>>>(is_train, ws, out);
}

// Round 23
// 376.112 us; speedup vs baseline: 3.2927x; 3.2927x over previous
//
#include <hip/hip_runtime.h>

#define EPSF 1e-5f

typedef _Float16 h2f  __attribute__((ext_vector_type(2)));
typedef _Float16 h8   __attribute__((ext_vector_type(8)));
typedef float    f32x4 __attribute__((ext_vector_type(4)));

#if defined(__has_builtin)
#if __has_builtin(__builtin_amdgcn_fdot2)
#define HAVE_FDOT2 1
#endif
#endif

__device__ __forceinline__ float fsig(float x){ return 1.0f/(1.0f+__expf(-x)); }
__device__ __forceinline__ float ftanh(float x){
  float e = __expf(2.f*x);
  float r = (e-1.f)/(e+1.f);
  return (x > 15.f) ? 1.f : ((x < -15.f) ? -1.f : r);
}
__device__ __forceinline__ int pkf(float lo, float hi){
  return __builtin_bit_cast(int, __builtin_amdgcn_cvt_pkrtz(lo, hi));
}
__device__ __forceinline__ int4 mk4(const float* p){
  return make_int4(pkf(p[0],p[1]),pkf(p[2],p[3]),pkf(p[4],p[5]),pkf(p[6],p[7]));
}
__device__ __forceinline__ float dot2(int w, int x, float acc){
#ifdef HAVE_FDOT2
  return __builtin_amdgcn_fdot2(__builtin_bit_cast(h2f, w),
                                __builtin_bit_cast(h2f, x), acc, false);
#else
  h2f a = __builtin_bit_cast(h2f, w), b = __builtin_bit_cast(h2f, x);
  return acc + (float)a[0]*(float)b[0] + (float)a[1]*(float)b[1];
#endif
}
__device__ __forceinline__ int rl_i(int v, int l){ return __builtin_amdgcn_readlane(v, l); }
__device__ __forceinline__ float rl_f(float v, int l){
  return __int_as_float(__builtin_amdgcn_readlane(__float_as_int(v), l));
}
#define MFMA(A,B,C) __builtin_amdgcn_mfma_f32_16x16x32_f16( \
    __builtin_bit_cast(h8,(A)), __builtin_bit_cast(h8,(B)), (C), 0,0,0)
// light barrier: order LDS only; global loads/stores stay in flight
#define BAR() do{ asm volatile("s_waitcnt lgkmcnt(0)" ::: "memory"); __builtin_amdgcn_s_barrier(); }while(0)

// ---------------------------------------------------------------------------
// Kernel 1: msum[t] = sum_{b,n} masks[b,t,n] + EPS   (one block per t)
// ---------------------------------------------------------------------------
__global__ void msum_kernel(const float* __restrict__ masks, float* __restrict__ msum){
  const int t   = blockIdx.x;
  const int tid = threadIdx.x;
  const int b0  = tid >> 3;
  const int n4  = (tid & 7) << 2;
  float s = 0.f;
  #pragma unroll 4
  for (int i = 0; i < 32; ++i) {
    const int b = b0 + (i << 5);
    const float4 v = *reinterpret_cast<const float4*>(masks + ((size_t)b*256 + t)*32 + n4);
    s += v.x + v.y + v.z + v.w;
  }
  __shared__ float red[256];
  red[tid] = s; __syncthreads();
  for (int off = 128; off > 0; off >>= 1) {
    if (tid < off) red[tid] += red[tid + off];
    __syncthreads();
  }
  if (tid == 0) msum[t] = red[0] + EPSF;
}

// ---------------------------------------------------------------------------
// Kernel 2: persistent RNN. 256 blocks x 512 threads, 4 batch elems / block.
// FINAL (r18, 379us, reproduced twice): chains on waves 0-3 (1/SIMD), gate
// GEMM via MFMA on all 8 waves, 2 light barriers/step. Critical-path
// reductions accumulated over 22 rounds: (1) gate weights as VGPR-resident
// f16x2 B-fragments (MFMA, no LDS weight traffic); (2) chain hist/feat
// weights VGPR-resident; (3) gamma_h + alpha matvecs precomputed in the E
// phase via MFMA from 2-deep-prefetched inputs (off the serial chain);
// (4) staging (cc/m/h/dw/gxw/mw) via direct per-lane b16 stores (no
// ds_bpermute packs, bank conflicts 6.3e6->1.05e6); (5) z-matvec via fp32
// readlane of x_c (no pack). Remaining wall is the algorithm's serial
// h(t)->x_h->c_c->gates->h(t+1) dependency x 256 steps at 1 runnable
// wave/SIMD (all TLP geometries blocked by register-budget/co-residency).
// ---------------------------------------------------------------------------
__global__ __launch_bounds__(512)
__attribute__((amdgpu_waves_per_eu(2, 2)))
void rits_kernel(
  const float* __restrict__ values, const float* __restrict__ masks,
  const float* __restrict__ deltas, const float* __restrict__ labels,
  const float* __restrict__ is_train,
  const float* __restrict__ td_h_W, const float* __restrict__ td_h_b,
  const float* __restrict__ td_x_W, const float* __restrict__ td_x_b,
  const float* __restrict__ hist_W, const float* __restrict__ hist_b,
  const float* __restrict__ feat_W, const float* __restrict__ feat_b,
  const float* __restrict__ wc_W,  const float* __restrict__ wc_b,
  const float* __restrict__ W_ih,  const float* __restrict__ W_hh,
  const float* __restrict__ b_ih,  const float* __restrict__ b_hh,
  const float* __restrict__ out_W, const float* __restrict__ out_b,
  const float* __restrict__ msum,
  float* __restrict__ xl_acc, float* __restrict__ bce_acc,
  float* __restrict__ predictions, float* __restrict__ imps)
{
  // [e][ cc 0..15 | m 16..31 | h 32..63 ] packed f16 pairs; stride 84
  // (84%32=20) -> rows 0..3 on distinct banks for same-word reads.
  __shared__ __align__(16) int  inp_s[4][84];
  // future words for E: [e][ dw 0..15 | gxw 16..31 | mw 32..47 ]; stride 52
  __shared__ __align__(16) int  nb[4][52];
  __shared__ float sB[4][64];     // gamma_h linear (pre-exp) for the step entered
  __shared__ float sAl[4][32];    // alpha for the step entered
  __shared__ float gp[4][256];    // [elem][gate row]  (raw, F activates)
  __shared__ float msum_l[256];   // 1/msum[t]

  const int tid = threadIdx.x;
  const int b   = blockIdx.x;
  const int wv  = tid >> 6;          // 0..7
  const int ln  = tid & 63;
  const bool chain = (wv < 4);
  const int me  = wv & 3;
  const int b2  = (b << 2) | me;
  const int kg  = ln >> 4;
  const int arow = ln & 15;

  if (tid < 256) msum_l[tid] = 1.0f / msum[tid];

  // ---- per-thread gate B-fragments (all 8 waves): 2 n-tiles x 4 k-steps ----
  int4 Wb[2][4];
  #pragma unroll
  for (int nt = 0; nt < 2; ++nt){
    const int col = (wv << 5) + (nt << 4) + (ln & 15);
    #pragma unroll
    for (int ks = 0; ks < 4; ++ks){
      const int k0 = (ks << 5) + (kg << 3);
      const float* src = (k0 < 64) ? (W_ih + (size_t)col*64 + k0)
                                   : (W_hh + (size_t)col*64 + (k0 - 64));
      Wb[nt][ks] = make_int4(pkf(src[0],src[1]), pkf(src[2],src[3]),
                             pkf(src[4],src[5]), pkf(src[6],src[7]));
    }
  }
  const int col0 = (wv << 5) + (ln & 15);
  const float bs0 = b_ih[col0]      + b_hh[col0];
  const float bs1 = b_ih[col0 + 16] + b_hh[col0 + 16];

  // ---- E-wave extra fragments: gamma_h (waves 4-7) + alpha (waves 4-5) ----
  int4 fGh = make_int4(0,0,0,0);
  float ghb = 0.f; int colj = 0;
  int4 fA0 = make_int4(0,0,0,0), fA1 = make_int4(0,0,0,0);
  float alb = 0.f; int colA = 0;
  if (wv >= 4){
    colj = ((wv - 4) << 4) | (ln & 15);
    fGh  = mk4(td_h_W + colj*32 + kg*8);
    ghb  = td_h_b[colj];
    if (wv < 6){
      colA = ((wv - 4) << 4) | (ln & 15);
      fA0  = mk4(wc_W + colA*64 + kg*8);
      fA1  = mk4(wc_W + colA*64 + 32 + kg*8);
      alb  = wc_b[colA];
    }
  }

  // ---- chain-wave VGPR weights + registers ----
  int4  fC[8];      // hist_W row (ln&31) (K=64)
  float wz[32];     // feat_W row (ln&31), fp32, diag 0
  float tdxd_r=0.f, tdxb_r=0.f, histb_r=0.f, featb_r=0.f;
  float xv=0.f, mv=0.f, dv=0.f;
  if (chain){
    const int nr = ln & 31;
    #pragma unroll
    for (int g = 0; g < 8; ++g) fC[g] = mk4(hist_W + nr*64 + 8*g);
    #pragma unroll
    for (int k = 0; k < 32; ++k) wz[k] = (k==nr) ? 0.f : feat_W[nr*32 + k];
    if (ln < 32){
      tdxd_r  = td_x_W[ln*33];
      tdxb_r  = td_x_b[ln];
      histb_r = hist_b[ln];
      featb_r = feat_b[ln];
      const size_t base = (size_t)b2*8192 + ln;
      xv = values[base]; mv = masks[base]; dv = deltas[base];
    }
  }
  float h_reg = 0.f, c_reg = 0.f, loss_acc = 0.f;
  const int i0 = (2*ln) & 63, i1 = (2*ln+1) & 63;

  __syncthreads();

  // ---- prologue: nb(0) via b16 stores ; E computes sB(0), sAl(0) ----
  if (chain && ln < 32){
    _Float16* np = reinterpret_cast<_Float16*>(&nb[me][0]);
    const float gx0 = __expf(-fmaxf(fmaf(dv, tdxd_r, tdxb_r), 0.f));
    np[ln]      = (_Float16)dv;
    np[32 + ln] = (_Float16)gx0;
    np[64 + ln] = (_Float16)mv;
  }
  __syncthreads();
  if (wv >= 4){
    int4 A = make_int4(0,0,0,0);
    if (arow < 4) A = *reinterpret_cast<const int4*>(&nb[arow][kg << 2]);
    f32x4 acc = {ghb, ghb, ghb, ghb};
    acc = MFMA(A, fGh, acc);
    if (kg == 0){
      #pragma unroll
      for (int e = 0; e < 4; ++e) sB[e][colj] = acc[e];
    }
    if (wv < 6){
      int4 A0 = make_int4(0,0,0,0), A1 = make_int4(0,0,0,0);
      if (arow < 4){
        A0 = *reinterpret_cast<const int4*>(&nb[arow][16 + (kg << 2)]);
        A1 = *reinterpret_cast<const int4*>(&nb[arow][32 + (kg << 2)]);
      }
      f32x4 aacc = {alb, alb, alb, alb};
      aacc = MFMA(A0, fA0, aacc);
      aacc = MFMA(A1, fA1, aacc);
      if (kg == 0){
        #pragma unroll
        for (int e = 0; e < 4; ++e) sAl[e][colA] = aacc[e];
      }
    }
  }
  __syncthreads();

  for (int t = 0; t < 256; ++t){
    // ---- chain: decay + C + z + combine; staging via b16 stores ----
    if (chain){
      const float x_cur = xv, m_cur = mv;
      const float sb = sB[me][ln];
      const float al = (ln < 32) ? sAl[me][ln] : 0.f;
      if (ln < 32 && t < 255){
        const size_t base = (size_t)b2*8192 + (size_t)(t+1)*32 + ln;
        xv = values[base]; mv = masks[base]; dv = deltas[base];
      }
      _Float16* hp = reinterpret_cast<_Float16*>(&inp_s[me][0]);
      _Float16* np = reinterpret_cast<_Float16*>(&nb[me][0]);

      h_reg *= __expf(-fmaxf(sb, 0.f));
      hp[64 + ln] = (_Float16)h_reg;        // h halves (words 32..63), direct
      const int hw = pkf(__shfl(h_reg, i0), __shfl(h_reg, i1));   // for C matvec
      // C: x_h (32 rows, K=64, VGPR weights); x_c
      float xh_v = 0.f, x_c_v = 0.f;
      if (ln < 32){
        float a0 = histb_r, a1 = 0.f, a2 = 0.f, a3 = 0.f;
        #pragma unroll
        for (int g4 = 0; g4 < 8; ++g4){
          const int4 w = fC[g4];
          a0 = dot2(w.x, rl_i(hw, 4*g4+0), a0);
          a1 = dot2(w.y, rl_i(hw, 4*g4+1), a1);
          a2 = dot2(w.z, rl_i(hw, 4*g4+2), a2);
          a3 = dot2(w.w, rl_i(hw, 4*g4+3), a3);
        }
        xh_v  = (a0+a1)+(a2+a3);
        x_c_v = m_cur*x_cur + (1.f-m_cur)*xh_v;
      }
      // D: z (fp32 readlane of x_c), combine with precomputed alpha
      if (ln < 32){
        float z0 = featb_r, z1 = 0.f, z2 = 0.f, z3 = 0.f;
        #pragma unroll
        for (int k = 0; k < 32; k += 4){
          z0 = fmaf(rl_f(x_c_v, k+0), wz[k+0], z0);
          z1 = fmaf(rl_f(x_c_v, k+1), wz[k+1], z1);
          z2 = fmaf(rl_f(x_c_v, k+2), wz[k+2], z2);
          z3 = fmaf(rl_f(x_c_v, k+3), wz[k+3], z3);
        }
        const float z = (z0+z1)+(z2+z3);
        const float ch = al*z + (1.f-al)*xh_v;
        loss_acc += (fabsf(x_cur-xh_v)+fabsf(x_cur-z)+fabsf(x_cur-ch))*m_cur*msum_l[t];
        const float ccv = m_cur*x_cur + (1.f-m_cur)*ch;
        imps[(size_t)b2*8192 + (size_t)t*32 + ln] = ccv;
        hp[ln]      = (_Float16)ccv;        // cc halves (words 0..15), direct
        hp[32 + ln] = (_Float16)m_cur;      // m halves (words 16..31), direct
        // future words for E (dv/mv hold t+1), direct b16
        const float gxn = __expf(-fmaxf(fmaf(dv, tdxd_r, tdxb_r), 0.f));
        np[ln]      = (_Float16)dv;
        np[32 + ln] = (_Float16)gxn;
        np[64 + ln] = (_Float16)mv;
      }
    }

    BAR();   // inp_s, nb visible to all waves

    // ---- E: gate GEMM via MFMA (raw gates -> gp) ----
    {
      int4 A[4];
      if (arow < 4){
        #pragma unroll
        for (int ks = 0; ks < 4; ++ks)
          A[ks] = *reinterpret_cast<const int4*>(&inp_s[arow][(ks << 4) + (kg << 2)]);
      } else {
        #pragma unroll
        for (int ks = 0; ks < 4; ++ks) A[ks] = make_int4(0,0,0,0);
      }
      f32x4 acc0 = {bs0, bs0, bs0, bs0};
      f32x4 acc1 = {bs1, bs1, bs1, bs1};
      #pragma unroll
      for (int ks = 0; ks < 4; ++ks){
        acc0 = __builtin_amdgcn_mfma_f32_16x16x32_f16(
                 __builtin_bit_cast(h8, A[ks]), __builtin_bit_cast(h8, Wb[0][ks]), acc0, 0,0,0);
        acc1 = __builtin_amdgcn_mfma_f32_16x16x32_f16(
                 __builtin_bit_cast(h8, A[ks]), __builtin_bit_cast(h8, Wb[1][ks]), acc1, 0,0,0);
      }
      // C/D: col=lane&15, row=(lane>>4)*4+reg -> kg==0 lanes hold rows 0-3
      if (kg == 0){
        #pragma unroll
        for (int e = 0; e < 4; ++e){
          gp[e][col0]      = acc0[e];
          gp[e][col0 + 16] = acc1[e];
        }
      }
    }
    // ---- E extra: gamma_h(t+1) (waves 4-7); alpha(t+1) (waves 4-5) ----
    if (wv >= 4){
      int4 Agh = make_int4(0,0,0,0);
      if (arow < 4) Agh = *reinterpret_cast<const int4*>(&nb[arow][kg << 2]);
      f32x4 accg = {ghb, ghb, ghb, ghb};
      accg = MFMA(Agh, fGh, accg);
      if (kg == 0){
        #pragma unroll
        for (int e = 0; e < 4; ++e) sB[e][colj] = accg[e];
      }
      if (wv < 6){
        int4 A0 = make_int4(0,0,0,0), A1 = make_int4(0,0,0,0);
        if (arow < 4){
          A0 = *reinterpret_cast<const int4*>(&nb[arow][16 + (kg << 2)]);
          A1 = *reinterpret_cast<const int4*>(&nb[arow][32 + (kg << 2)]);
        }
        f32x4 aacc = {alb, alb, alb, alb};
        aacc = MFMA(A0, fA0, aacc);
        aacc = MFMA(A1, fA1, aacc);
        if (kg == 0){
          #pragma unroll
          for (int e = 0; e < 4; ++e) sAl[e][colA] = aacc[e];
        }
      }
    }

    BAR();   // gates + sB + sAl visible to chain waves

    // ---- F: LSTM pointwise update (chain waves) ----
    if (chain){
      const float ig = gp[me][ln];
      const float fg = gp[me][64+ln];
      const float gg = gp[me][128+ln];
      const float og = gp[me][192+ln];
      c_reg = fsig(fg)*c_reg + fsig(ig)*ftanh(gg);
      h_reg = fsig(og)*ftanh(c_reg);
    }
  }

  // ---- epilogue: loss reduce + prediction/BCE (chain waves) ----
  if (chain){
    float l = loss_acc;   // nonzero only on ln<32
    l += __shfl_xor(l,16); l += __shfl_xor(l,8);
    l += __shfl_xor(l,4);  l += __shfl_xor(l,2); l += __shfl_xor(l,1);
    if (ln == 0) atomicAdd(xl_acc, l);

    float p = h_reg * out_W[ln];
    p += __shfl_xor(p,32); p += __shfl_xor(p,16); p += __shfl_xor(p,8);
    p += __shfl_xor(p,4);  p += __shfl_xor(p,2);  p += __shfl_xor(p,1);
    if (ln == 0){
      const float y = p + out_b[0];
      predictions[b2] = fsig(y);
      const float lab = labels[b2];
      const float it  = is_train[b2];
      const float mx  = fmaxf(-y, 0.f);
      const float bce = y - y*lab + mx + __logf(__expf(-mx) + __expf(-y - mx));
      atomicAdd(bce_acc, bce * it);
    }
  }
}

// ---------------------------------------------------------------------------
// Kernel 3: finalize loss scalar
// ---------------------------------------------------------------------------
__global__ void final_kernel(const float* __restrict__ is_train,
                             const float* __restrict__ ws,
                             float* __restrict__ out){
  const int tid = threadIdx.x;
  __shared__ float red[256];
  red[tid] = is_train[tid] + is_train[tid+256] + is_train[tid+512] + is_train[tid+768];
  __syncthreads();
  for (int off = 128; off > 0; off >>= 1){
    if (tid < off) red[tid] += red[tid + off];
    __syncthreads();
  }
  if (tid == 0){
    const float yl = ws[1] / (red[0] + EPSF);
    out[0] = ws[0] / 256.0f + 0.1f * yl;
  }
}

extern "C" void kernel_launch(void* const* d_in, const int* in_sizes, int n_in,
                              void* d_out, int out_size, void* d_ws, size_t ws_size,
                              hipStream_t stream){
  const float* values   = (const float*)d_in[0];
  const float* masks    = (const float*)d_in[1];
  const float* deltas   = (const float*)d_in[2];
  const float* labels   = (const float*)d_in[5];
  const float* is_train = (const float*)d_in[6];
  const float* td_h_W   = (const float*)d_in[7];
  const float* td_h_b   = (const float*)d_in[8];
  const float* td_x_W   = (const float*)d_in[9];
  const float* td_x_b   = (const float*)d_in[10];
  const float* hist_W   = (const float*)d_in[11];
  const float* hist_b   = (const float*)d_in[12];
  const float* feat_W   = (const float*)d_in[13];
  const float* feat_b   = (const float*)d_in[14];
  const float* wc_W     = (const float*)d_in[15];
  const float* wc_b     = (const float*)d_in[16];
  const float* W_ih     = (const float*)d_in[17];
  const float* W_hh     = (const float*)d_in[18];
  const float* b_ih     = (const float*)d_in[19];
  const float* b_hh     = (const float*)d_in[20];
  const float* out_W    = (const float*)d_in[21];
  const float* out_b    = (const float*)d_in[22];

  float* out = (float*)d_out;                 // [0]=loss, [1..1025)=preds, [1025..)=imps
  float* ws  = (float*)d_ws;                  // [0]=xl_sum, [1]=bce_sum, [2..258)=msum

  hipMemsetAsync(ws, 0, 2*sizeof(float), stream);
  msum_kernel<<<256, 256, 0, stream>>>(masks, ws + 2);
  rits_kernel<<<256, 512, 0, stream>>>(values, masks, deltas, labels, is_train,
      td_h_W, td_h_b, td_x_W, td_x_b, hist_W, hist_b, feat_W, feat_b,
      wc_W, wc_b, W_ih, W_hh, b_ih, b_hh, out_W, out_b,
      ws + 2, ws + 0, ws + 1, out + 1, out + 1 + 1024);
  final_kernel<<<1, 256, 0, stream>>>(is_train, ws, out);
}